// Round 8
// baseline (421.831 us; speedup 1.0000x reference)
//
#include <hip/hip_runtime.h>
#include <hip/hip_bf16.h>
#include <stdint.h>

typedef unsigned short u16;
typedef __attribute__((ext_vector_type(8))) short short8;
typedef __attribute__((ext_vector_type(4))) float f32x4;

#define DIM 128
#define CAP 64   // per-node bucket capacity; deg ~ Poisson(16), P(deg>=64) ~ 2e-18/node
#define LDS_STRIDE 136  // u16 units; 272B row stride -> 2-way LDS bank alias (free)

__device__ __forceinline__ float bflo(uint32_t v) {
    uint32_t b = v << 16;
    float f; __builtin_memcpy(&f, &b, 4); return f;
}
__device__ __forceinline__ float bfhi(uint32_t v) {
    uint32_t b = v & 0xffff0000u;
    float f; __builtin_memcpy(&f, &b, 4); return f;
}
__device__ __forceinline__ u16 f2bf(float f) {
    uint32_t x; __builtin_memcpy(&x, &f, 4);
    uint32_t r = (x + 0x7fffu + ((x >> 16) & 1u)) >> 16;
    return (u16)r;
}
__device__ __forceinline__ uint32_t pack2bf(float a, float b) {
    return (uint32_t)f2bf(a) | ((uint32_t)f2bf(b) << 16);
}
__device__ __forceinline__ void accum8(float* a, uint4 v) {
    a[0] += bflo(v.x); a[1] += bfhi(v.x);
    a[2] += bflo(v.y); a[3] += bfhi(v.y);
    a[4] += bflo(v.z); a[5] += bfhi(v.z);
    a[6] += bflo(v.w); a[7] += bfhi(v.w);
}

// ---------------- sort-based CSR build (no per-edge global atomics) ----------------

__global__ __launch_bounds__(256) void k_bin1(
    const int* __restrict__ src, const int* __restrict__ dst,
    uint32_t* __restrict__ gCur, uint32_t* __restrict__ groupBuf,
    int E, int ngrp, int gcap)
{
    __shared__ uint32_t hcnt[512];
    __shared__ uint32_t hbase[512];
    __shared__ uint32_t hcur[512];
    int nb = gridDim.x;
    int per = (E + nb - 1) / nb;
    int lo = blockIdx.x * per;
    int hi = lo + per; if (hi > E) hi = E;

    for (int t = threadIdx.x; t < ngrp; t += 256) { hcnt[t] = 0; hcur[t] = 0; }
    __syncthreads();

    for (int i = lo + threadIdx.x; i < hi; i += 256)
        atomicAdd(&hcnt[((uint32_t)dst[i]) >> 8], 1u);
    __syncthreads();

    int rot = (blockIdx.x * 37) % (ngrp > 0 ? ngrp : 1);
    for (int k = threadIdx.x; k < ngrp; k += 256) {
        int t = k + rot; if (t >= ngrp) t -= ngrp;
        uint32_t c = hcnt[t];
        hbase[t] = c ? atomicAdd(&gCur[t], c) : 0u;
    }
    __syncthreads();

    for (int i = lo + threadIdx.x; i < hi; i += 256) {
        uint32_t d = (uint32_t)dst[i];
        uint32_t g = d >> 8;
        uint32_t off = hbase[g] + atomicAdd(&hcur[g], 1u);
        if (off < (uint32_t)gcap)
            groupBuf[(size_t)g * gcap + off] = (uint32_t)src[i] | ((d & 255u) << 20);
    }
}

__global__ __launch_bounds__(256) void k_bin2(
    const uint32_t* __restrict__ groupBuf, const uint32_t* __restrict__ gCur,
    uint32_t* __restrict__ bucket, uint32_t* __restrict__ cnt,
    int N, int gcap)
{
    __shared__ uint32_t ncur[256];
    int g = blockIdx.x;
    ncur[threadIdx.x] = 0;
    __syncthreads();
    uint32_t m = gCur[g]; if (m > (uint32_t)gcap) m = gcap;
    int nodebase = g << 8;
    const uint32_t* buf = groupBuf + (size_t)g * gcap;
    for (uint32_t i = threadIdx.x; i < m; i += 256) {
        uint32_t v = buf[i];
        uint32_t nl = v >> 20;
        uint32_t s = v & 0xFFFFFu;
        uint32_t pos = atomicAdd(&ncur[nl], 1u);   // LDS atomic
        if (pos < CAP) bucket[(size_t)(nodebase + (int)nl) * CAP + pos] = s;
    }
    __syncthreads();
    int node = nodebase + threadIdx.x;
    if (node < N) cnt[node] = ncur[threadIdx.x];
}

// ---------------- feature cast f32 -> bf16 (once per call) ----------------

__global__ void k_cast(const float* __restrict__ in, uint32_t* __restrict__ out, int n4) {
    int i = blockIdx.x * blockDim.x + threadIdx.x;
    int stride = gridDim.x * blockDim.x;
    const float4* in4 = (const float4*)in;
    uint2* out2 = (uint2*)out;
    for (; i < n4; i += stride) {
        float4 v = in4[i];
        uint2 r;
        r.x = pack2bf(v.x, v.y);
        r.y = pack2bf(v.z, v.w);
        out2[i] = r;
    }
}

// ---------------- weight transpose f32 -> bf16 (once per call) ----------------

__global__ void k_transpose3(const float* __restrict__ w0, const float* __restrict__ w1,
                             const float* __restrict__ w2, u16* __restrict__ t0,
                             u16* __restrict__ t1, u16* __restrict__ t2) {
    const float* w = blockIdx.x == 0 ? w0 : (blockIdx.x == 1 ? w1 : w2);
    u16* o = blockIdx.x == 0 ? t0 : (blockIdx.x == 1 ? t1 : t2);
    for (int idx = threadIdx.x; idx < DIM * DIM; idx += blockDim.x) {
        int r = idx >> 7, c = idx & 127;
        o[c * DIM + r] = f2bf(w[idx]);
    }
}

// ---------------- fused gather + LN + GEMM ----------------
// Block = 256 thr (4 waves) = 32 nodes. Wave w gathers nodes w*8..w*8+7:
//   quarter q (lanes 16q..16q+15) processes edges e+q of each 4-edge batch;
//   lane (m = l&15) loads uint4 = dims 8m..8m+7 of the source row.
//   Cross-quarter shfl reduce, 16-lane LN reduce, pack bf16 -> LDS row.
// Then 32x128 MFMA GEMM with A from LDS, B (wt) from global, out to global.
// NOTE: xin and outp MUST be distinct buffers (no in-place layer update).

template <int RELU, int OUTF32>
__global__ __launch_bounds__(256) void k_fused(
    const uint32_t* __restrict__ xin, const uint32_t* __restrict__ cnt,
    const uint32_t* __restrict__ bucket,
    const int* __restrict__ src, const int* __restrict__ dst,
    const float* __restrict__ gamma, const float* __restrict__ beta,
    const u16* __restrict__ wt, const float* __restrict__ bias,
    void* __restrict__ outp, int N, int E)
{
    __shared__ u16 lds[32 * LDS_STRIDE];
    int w = threadIdx.x >> 6, l = threadIdx.x & 63;
    int q = l >> 4, m = l & 15;
    int nodebase = blockIdx.x * 32;
    const uint4* x4 = (const uint4*)xin;

    // ---- phase 1: gather + LN, 8 nodes per wave ----
    for (int nn = 0; nn < 8; ++nn) {
        int node = nodebase + w * 8 + nn;
        float acc[8] = {0.f,0.f,0.f,0.f,0.f,0.f,0.f,0.f};
        uint32_t c = (node < N) ? cnt[node] : 0u;
        if (__builtin_expect(c > CAP, 0)) {
            // overflow fallback: raw edge scan; only quarter 0 accumulates
            for (int e = 0; e < E; ++e) {
                if (dst[e] == node && q == 0) {
                    uint4 v = x4[(size_t)src[e] * 16 + m];
                    accum8(acc, v);
                }
            }
        } else {
            const uint32_t* bkt = bucket + (size_t)node * CAP;
            uint32_t e = 0;
            while (e + 16 <= c) {   // 16 edges: 4 independent 16B loads per lane
                uint32_t s0 = bkt[e + 0  + q];
                uint32_t s1 = bkt[e + 4  + q];
                uint32_t s2 = bkt[e + 8  + q];
                uint32_t s3 = bkt[e + 12 + q];
                uint4 v0 = x4[(size_t)s0 * 16 + m];
                uint4 v1 = x4[(size_t)s1 * 16 + m];
                uint4 v2 = x4[(size_t)s2 * 16 + m];
                uint4 v3 = x4[(size_t)s3 * 16 + m];
                accum8(acc, v0); accum8(acc, v1); accum8(acc, v2); accum8(acc, v3);
                e += 16;
            }
            while (e < c) {         // tail: 4 edges per iter, per-quarter predicate
                uint32_t idx = e + (uint32_t)q;
                if (idx < c) {
                    uint4 v = x4[(size_t)bkt[idx] * 16 + m];
                    accum8(acc, v);
                }
                e += 4;
            }
        }
        // cross-quarter reduce (quarters held disjoint edge subsets)
#pragma unroll
        for (int j = 0; j < 8; ++j) {
            acc[j] += __shfl_xor(acc[j], 32, 64);
            acc[j] += __shfl_xor(acc[j], 16, 64);
        }
        // LN stats over 128 dims: in-lane 8, then 16 lanes
        float sum = 0.f, sq = 0.f;
#pragma unroll
        for (int j = 0; j < 8; ++j) { sum += acc[j]; sq += acc[j] * acc[j]; }
        for (int off = 8; off; off >>= 1) {
            sum += __shfl_xor(sum, off, 64);
            sq  += __shfl_xor(sq,  off, 64);
        }
        float mean = sum * (1.f / 128.f);
        float var  = sq * (1.f / 128.f) - mean * mean;
        float rs   = rsqrtf(var + 1e-5f);
        float4 ga = ((const float4*)gamma)[m * 2];
        float4 gb = ((const float4*)gamma)[m * 2 + 1];
        float4 ba = ((const float4*)beta)[m * 2];
        float4 bb = ((const float4*)beta)[m * 2 + 1];
        if (q == 0) {
            uint4 o;
            o.x = pack2bf((acc[0]-mean)*rs*ga.x+ba.x, (acc[1]-mean)*rs*ga.y+ba.y);
            o.y = pack2bf((acc[2]-mean)*rs*ga.z+ba.z, (acc[3]-mean)*rs*ga.w+ba.w);
            o.z = pack2bf((acc[4]-mean)*rs*gb.x+bb.x, (acc[5]-mean)*rs*gb.y+bb.y);
            o.w = pack2bf((acc[6]-mean)*rs*gb.z+bb.z, (acc[7]-mean)*rs*gb.w+bb.w);
            *(uint4*)&lds[(w * 8 + nn) * LDS_STRIDE + m * 8] = o;
        }
    }
    __syncthreads();

    // ---- phase 2: GEMM 32x128 (A from LDS, B from wt) ----
    int row0loc = 16 * (w & 1);
    int colbase = (w >> 1) * 64;

    short8 afrag[4];
#pragma unroll
    for (int kc = 0; kc < 4; ++kc)
        afrag[kc] = *(const short8*)&lds[(row0loc + m) * LDS_STRIDE + kc * 32 + q * 8];

    short8 bfrag[4][4];
#pragma unroll
    for (int ct = 0; ct < 4; ++ct)
#pragma unroll
        for (int kc = 0; kc < 4; ++kc)
            bfrag[ct][kc] = *(const short8*)(wt + (size_t)(colbase + ct * 16 + m) * DIM + kc * 32 + q * 8);

    f32x4 accm[4];
#pragma unroll
    for (int ct = 0; ct < 4; ++ct) {
        f32x4 a = {0.f, 0.f, 0.f, 0.f};
#pragma unroll
        for (int kc = 0; kc < 4; ++kc)
            a = __builtin_amdgcn_mfma_f32_16x16x32_bf16(afrag[kc], bfrag[ct][kc], a, 0, 0, 0);
        accm[ct] = a;
    }

#pragma unroll
    for (int ct = 0; ct < 4; ++ct) {
        int col = colbase + ct * 16 + m;
        float bv = bias[col];
#pragma unroll
        for (int j = 0; j < 4; ++j) {
            int row = nodebase + row0loc + q * 4 + j;
            float v = accm[ct][j] + bv;
            if (RELU) v = fmaxf(v, 0.f);
            if (row < N) {
                if (OUTF32) ((float*)outp)[(size_t)row * DIM + col] = v;
                else        ((u16*)outp)[(size_t)row * DIM + col] = f2bf(v);
            }
        }
    }
}

// ---------------- launch ----------------

extern "C" void kernel_launch(void* const* d_in, const int* in_sizes, int n_in,
                              void* d_out, int out_size, void* d_ws, size_t ws_size,
                              hipStream_t stream) {
    const float* feat = (const float*)d_in[0];
    const int* src  = (const int*)d_in[1];
    const int* dst  = (const int*)d_in[2];
    const float* g1 = (const float*)d_in[3],  *be1 = (const float*)d_in[4];
    const float* W1 = (const float*)d_in[5],  *b1  = (const float*)d_in[6];
    const float* g2 = (const float*)d_in[7],  *be2 = (const float*)d_in[8];
    const float* W2 = (const float*)d_in[9],  *b2  = (const float*)d_in[10];
    const float* g3 = (const float*)d_in[11], *be3 = (const float*)d_in[12];
    const float* W3 = (const float*)d_in[13], *b3  = (const float*)d_in[14];

    int N = in_sizes[0] / DIM;
    int E = in_sizes[1];
    float* out = (float*)d_out;

    int ngrp = (N + 255) >> 8;                 // 391 for N=100000 (max 512)
    int gcap = (E / (ngrp > 0 ? ngrp : 1)) * 3 / 2 + 1024;

    char* ws = (char*)d_ws;
    auto alloc = [&](size_t bytes) {
        char* p = ws;
        ws += (bytes + 255) & ~(size_t)255;
        return p;
    };
    uint32_t* gCur     = (uint32_t*)alloc((size_t)ngrp * 4);
    uint32_t* groupBuf = (uint32_t*)alloc((size_t)ngrp * gcap * 4);
    uint32_t* cnt      = (uint32_t*)alloc((size_t)N * 4);
    uint32_t* bucket   = (uint32_t*)alloc((size_t)N * CAP * 4);
    u16* wt1 = (u16*)alloc(DIM * DIM * 2);
    u16* wt2 = (u16*)alloc(DIM * DIM * 2);
    u16* wt3 = (u16*)alloc(DIM * DIM * 2);
    uint32_t* X0 = (uint32_t*)alloc((size_t)N * 64 * 4);  // bf16-packed features
    uint32_t* X1 = (uint32_t*)alloc((size_t)N * 64 * 4);  // layer-1 out (ping)
    uint32_t* X2 = (uint32_t*)alloc((size_t)N * 64 * 4);  // layer-2 out (pong)

    hipMemsetAsync(gCur, 0, (size_t)ngrp * 4, stream);
    k_bin1<<<256, 256, 0, stream>>>(src, dst, gCur, groupBuf, E, ngrp, gcap);
    k_bin2<<<ngrp, 256, 0, stream>>>(groupBuf, gCur, bucket, cnt, N, gcap);
    k_transpose3<<<3, 256, 0, stream>>>(W1, W2, W3, wt1, wt2, wt3);
    k_cast<<<1024, 256, 0, stream>>>(feat, X0, N * 32);

    int fblocks = (N + 31) / 32;

    // ping-pong buffers: fused kernel must never read and write the same buffer
    k_fused<1, 0><<<fblocks, 256, 0, stream>>>(X0, cnt, bucket, src, dst, g1, be1, wt1, b1, X1,  N, E);
    k_fused<1, 0><<<fblocks, 256, 0, stream>>>(X1, cnt, bucket, src, dst, g2, be2, wt2, b2, X2,  N, E);
    k_fused<0, 1><<<fblocks, 256, 0, stream>>>(X2, cnt, bucket, src, dst, g3, be3, wt3, b3, out, N, E);
}